// Round 8
// baseline (509.746 us; speedup 1.0000x reference)
//
#include <hip/hip_runtime.h>
#include <hip/hip_bf16.h>

#define TPB 256
#define TPA 512

typedef __attribute__((ext_vector_type(8))) short bf16x8;
typedef __attribute__((ext_vector_type(4))) float f32x4;

static __device__ __forceinline__ unsigned short f2bf(float f) {
  union { float f; unsigned int u; } x; x.f = f;
  unsigned int r = x.u + 0x7FFF + ((x.u >> 16) & 1);   // RNE
  return (unsigned short)(r >> 16);
}
static __device__ __forceinline__ float bf2f(unsigned short h) {
  union { unsigned int u; float f; } x; x.u = ((unsigned int)h) << 16;
  return x.f;
}

#define MFMA16(a, b, c) __builtin_amdgcn_mfma_f32_16x16x32_bf16(a, b, c, 0, 0, 0)

// ---------------------------------------------------------------------------
// Augmented fold GEMM: C(51,Nc) = [A(50,K); lastrow(K)] @ W(K,Nc), bias added
// to row 50 only. mode 0: fp32 C row-major (51 rows).
// mode 1: rows 0..49 (51..63 zero) -> WfT_hi/WfT_lo [col][64] bf16 split,
//         k index pre-XOR-swizzled; row 50 -> bfv fp32.
// ---------------------------------------------------------------------------
__global__ __launch_bounds__(TPB) void gemm_fold_k(
    const float* __restrict__ A, const float* __restrict__ lastrow,
    const float* __restrict__ W, const float* __restrict__ bias,
    float* __restrict__ C, unsigned short* __restrict__ WfTh,
    unsigned short* __restrict__ WfTl, float* __restrict__ bfv,
    int K, int Nc, int mode)
{
  __shared__ float As[16][68];
  __shared__ float Ws[16][68];
  int tid = threadIdx.x;
  int col0 = blockIdx.x * 64;
  int ty = tid >> 4, tx = tid & 15;
  float acc[4][4] = {};
  for (int k0 = 0; k0 < K; k0 += 16) {
#pragma unroll
    for (int i = 0; i < 4; ++i) {
      int idx = tid + i * 256;
      int r = idx >> 4, kk = idx & 15;
      int gk = k0 + kk;
      float v = 0.f;
      if (gk < K) {
        if (r < 50) v = A[(size_t)r * K + gk];
        else if (r == 50) v = lastrow[gk];
      }
      As[kk][r] = v;
    }
#pragma unroll
    for (int i = 0; i < 4; ++i) {
      int idx = tid + i * 256;
      int c = idx & 63, kk = idx >> 6;
      int gc = col0 + c, gk = k0 + kk;
      float v = 0.f;
      if (gk < K && gc < Nc) v = W[(size_t)gk * Nc + gc];
      Ws[kk][c] = v;
    }
    __syncthreads();
#pragma unroll
    for (int kk = 0; kk < 16; ++kk) {
      float4 a4 = *(const float4*)&As[kk][ty * 4];
      float4 b4 = *(const float4*)&Ws[kk][tx * 4];
      float av[4] = {a4.x, a4.y, a4.z, a4.w};
      float bv[4] = {b4.x, b4.y, b4.z, b4.w};
#pragma unroll
      for (int i = 0; i < 4; ++i)
#pragma unroll
        for (int j = 0; j < 4; ++j)
          acc[i][j] = fmaf(av[i], bv[j], acc[i][j]);
    }
    __syncthreads();
  }
#pragma unroll
  for (int i = 0; i < 4; ++i) {
    int gr = ty * 4 + i;
#pragma unroll
    for (int j = 0; j < 4; ++j) {
      int gc = col0 + tx * 4 + j;
      if (gc >= Nc) continue;
      float v = acc[i][j];
      if (gr == 50) v += bias[gc];
      if (mode == 0) {
        if (gr < 51) C[(size_t)gr * Nc + gc] = v;
      } else {
        if (gr == 50) bfv[gc] = v;
        else {
          unsigned short hi = f2bf(v);
          size_t el = (size_t)gc * 64 + (gr ^ ((gc & 7) * 8));
          WfTh[el] = hi;
          WfTl[el] = f2bf(v - bf2f(hi));
        }
      }
    }
  }
}

// ---------------------------------------------------------------------------
// Split-precision MFMA ruv GEMM: [7688 x 50(->64)] @ Wf -> RU bf16 + Vt bf16.
// x ~ x_hi + x_lo, Wf ~ Wf_hi + Wf_lo (bf16 each); compute
// x_hi@W_hi + x_lo@W_hi + x_hi@W_lo (lo.lo dropped) -> fp32-accurate,
// single final rounding to bf16. Block 64 rows x 256 cols, 4 waves.
// Grid (9, 121). Col blocks 0..5 -> RU, 6..8 -> Vt (transposed, hb=h*8+b).
// ---------------------------------------------------------------------------
__global__ __launch_bounds__(TPB) void gemm_ruv_mfma_k(
    const float* __restrict__ x,              // [7688][50]
    const unsigned short* __restrict__ WfTh,  // [2304][64] bf16 swizzled
    const unsigned short* __restrict__ WfTl,  // [2304][64] bf16 swizzled
    const float* __restrict__ bias,           // [2304] fp32
    unsigned short* __restrict__ RU,          // [7688][1536]
    unsigned short* __restrict__ Vt)          // [hb][64][968]
{
  __shared__ unsigned short Bl[256 * 64];     // 32 KB
  int tid = threadIdx.x, w = tid >> 6, lane = tid & 63;
  int g = lane >> 4, c = lane & 15;
  int m0 = blockIdx.y * 64;
  int col0 = blockIdx.x * 256;
  int wc0 = w * 64;

  // ---- A fragments hi/lo from global x ----
  bf16x8 afh[4][2], afl[4][2];
#pragma unroll
  for (int rt = 0; rt < 4; ++rt) {
    int row = m0 + rt * 16 + c;
    if (row > 7687) row = 7687;
    const float* xr = x + (size_t)row * 50;
#pragma unroll
    for (int kk = 0; kk < 2; ++kk) {
      bf16x8 ah, al;
#pragma unroll
      for (int i = 0; i < 8; ++i) {
        int k = kk * 32 + g * 8 + i;
        float v = (k < 50) ? xr[k] : 0.f;
        unsigned short hi = f2bf(v);
        ah[i] = (short)hi;
        al[i] = (short)f2bf(v - bf2f(hi));
      }
      afh[rt][kk] = ah;
      afl[rt][kk] = al;
    }
  }

  // ---- stage B = Wf_hi ----
#pragma unroll
  for (int it = 0; it < 8; ++it) {
    int chunk = tid + it * 256;
    int colr = chunk >> 3, s = chunk & 7;
    *(int4*)&Bl[colr * 64 + s * 8] =
        *(const int4*)&WfTh[(size_t)(col0 + colr) * 64 + s * 8];
  }
  __syncthreads();

  f32x4 zero4 = {0.f, 0.f, 0.f, 0.f};
  f32x4 acc[4][4] = {{zero4, zero4, zero4, zero4}, {zero4, zero4, zero4, zero4},
                     {zero4, zero4, zero4, zero4}, {zero4, zero4, zero4, zero4}};

  // ---- pass 1: (x_hi + x_lo) @ Wf_hi ----
#pragma unroll
  for (int ct = 0; ct < 4; ++ct) {
    int bcol = wc0 + ct * 16 + c;
    int sw = (bcol & 7) * 8;
    bf16x8 b0 = *(const bf16x8*)&Bl[bcol * 64 + ((g * 8) ^ sw)];
    bf16x8 b1 = *(const bf16x8*)&Bl[bcol * 64 + ((32 + g * 8) ^ sw)];
#pragma unroll
    for (int rt = 0; rt < 4; ++rt) {
      acc[rt][ct] = MFMA16(afh[rt][0], b0, acc[rt][ct]);
      acc[rt][ct] = MFMA16(afh[rt][1], b1, acc[rt][ct]);
      acc[rt][ct] = MFMA16(afl[rt][0], b0, acc[rt][ct]);
      acc[rt][ct] = MFMA16(afl[rt][1], b1, acc[rt][ct]);
    }
  }
  __syncthreads();

  // ---- stage B = Wf_lo ----
#pragma unroll
  for (int it = 0; it < 8; ++it) {
    int chunk = tid + it * 256;
    int colr = chunk >> 3, s = chunk & 7;
    *(int4*)&Bl[colr * 64 + s * 8] =
        *(const int4*)&WfTl[(size_t)(col0 + colr) * 64 + s * 8];
  }
  __syncthreads();

  // ---- pass 2: x_hi @ Wf_lo ----
#pragma unroll
  for (int ct = 0; ct < 4; ++ct) {
    int bcol = wc0 + ct * 16 + c;
    int sw = (bcol & 7) * 8;
    bf16x8 b0 = *(const bf16x8*)&Bl[bcol * 64 + ((g * 8) ^ sw)];
    bf16x8 b1 = *(const bf16x8*)&Bl[bcol * 64 + ((32 + g * 8) ^ sw)];
#pragma unroll
    for (int rt = 0; rt < 4; ++rt) {
      acc[rt][ct] = MFMA16(afh[rt][0], b0, acc[rt][ct]);
      acc[rt][ct] = MFMA16(afh[rt][1], b1, acc[rt][ct]);
    }
  }

  // ---- epilogue: row = m0+rt*16+g*4+r, col = col0+wc0+ct*16+c ----
  bool isRU = (col0 < 1536);
#pragma unroll
  for (int ct = 0; ct < 4; ++ct) {
    int col = col0 + wc0 + ct * 16 + c;
    float bs = bias[col];
    if (isRU) {
#pragma unroll
      for (int rt = 0; rt < 4; ++rt) {
        int row0 = m0 + rt * 16 + g * 4;
#pragma unroll
        for (int r = 0; r < 4; ++r) {
          int row = row0 + r;
          if (row < 7688)
            RU[(size_t)row * 1536 + col] = f2bf(acc[rt][ct][r] + bs);
        }
      }
    } else {
      int hd = col - 1536;
      int hh = hd >> 6, d = hd & 63;
#pragma unroll
      for (int rt = 0; rt < 4; ++rt) {
        int row0 = m0 + rt * 16 + g * 4;
        int b0 = row0 / 961;
        int n0 = row0 - b0 * 961;
        if (row0 + 3 < 7688 && n0 <= 957 && (n0 & 3) == 0) {
          ushort4 o;
          o.x = f2bf(acc[rt][ct][0] + bs);
          o.y = f2bf(acc[rt][ct][1] + bs);
          o.z = f2bf(acc[rt][ct][2] + bs);
          o.w = f2bf(acc[rt][ct][3] + bs);
          *(ushort4*)&Vt[((size_t)(hh * 8 + b0) * 64 + d) * 968 + n0] = o;
        } else {
#pragma unroll
          for (int r = 0; r < 4; ++r) {
            int row = row0 + r;
            if (row >= 7688) continue;
            int bb = row / 961;
            int nn = row - bb * 961;
            Vt[((size_t)(hh * 8 + bb) * 64 + d) * 968 + nn] =
                f2bf(acc[rt][ct][r] + bs);
          }
        }
      }
    }
  }
}

// ---------------------------------------------------------------------------
// MFMA flash attention, QB=128 (512 threads, 8 waves of 16 q-rows each).
// K-tiles of 64 keys staged in LDS (XOR-swizzled); P per-wave in LDS.
// No-max softmax (logits bounded << 87); rowsum from bf16-rounded P.
// Grid (8, 96).
// ---------------------------------------------------------------------------
__global__ __launch_bounds__(TPA) void attn_mfma_k(
    const unsigned short* __restrict__ RU,   // [b*961][1536] bf16 bits
    const unsigned short* __restrict__ Vt,   // [hb][64][968] bf16 bits
    float* __restrict__ O)                   // [hb][961*64] fp32
{
  const int NS = 961, RS = 1536, VROW = 968;
  __shared__ unsigned short Kl[64 * 64];
  __shared__ unsigned short Vl[64 * 64];
  __shared__ unsigned short Pl[8][16 * 64];
  int hb = blockIdx.y;
  int h = hb >> 3, b = hb & 7;
  int n0 = blockIdx.x * 128;
  int tid = threadIdx.x;
  int w = tid >> 6, lane = tid & 63;
  int g = lane >> 4, c = lane & 15;
  const unsigned short* rubase = RU + (size_t)b * NS * RS;
  int roff = h * 64, uoff = 768 + h * 64;
  const unsigned short* vtbase = Vt + (size_t)hb * 64 * VROW;
  unsigned short* pw = &Pl[w][0];

  int qrow = n0 + w * 16 + c;
  if (qrow > 960) qrow = 960;
  bf16x8 qf0 = *(const bf16x8*)(rubase + (size_t)qrow * RS + roff + g * 8);
  bf16x8 qf1 = *(const bf16x8*)(rubase + (size_t)qrow * RS + roff + 32 + g * 8);

  f32x4 zero4 = {0.f, 0.f, 0.f, 0.f};
  f32x4 oacc[4] = {zero4, zero4, zero4, zero4};
  float rowsum[4] = {0.f, 0.f, 0.f, 0.f};

  for (int kt = 0; kt < 16; ++kt) {
    // ---- stage K(u) and V tiles: 512 chunks each, one per thread ----
    {
      int row = tid >> 3, s = tid & 7;
      int keyg = kt * 64 + row;
      int kcl = keyg > 960 ? 960 : keyg;
      ushort4 ka = *(const ushort4*)(rubase + (size_t)kcl * RS + uoff + s * 8);
      ushort4 kb = *(const ushort4*)(rubase + (size_t)kcl * RS + uoff + s * 8 + 4);
      int kel = row * 64 + 8 * (s ^ (row & 7));
      *(ushort4*)&Kl[kel] = ka;
      *(ushort4*)&Kl[kel + 4] = kb;

      int d = row;
      int koff = kt * 64 + s * 8;
      ushort4 va = *(const ushort4*)(vtbase + (size_t)d * VROW + koff);
      ushort4 vb = *(const ushort4*)(vtbase + (size_t)d * VROW + koff + 4);
      unsigned short vv[8] = {va.x, va.y, va.z, va.w, vb.x, vb.y, vb.z, vb.w};
#pragma unroll
      for (int e = 0; e < 8; ++e)
        if (koff + e > 960) vv[e] = 0;
      int vel = d * 64 + 8 * (s ^ (d & 7));
#pragma unroll
      for (int e = 0; e < 8; ++e) Vl[vel + e] = vv[e];
    }
    __syncthreads();

    // ---- QK^T ----
    f32x4 sa[4] = {zero4, zero4, zero4, zero4};
#pragma unroll
    for (int ct = 0; ct < 4; ++ct) {
      int key = c * 4 + ct;
      const bf16x8* kf0 = (const bf16x8*)&Kl[key * 64 + ((g * 8) ^ ((key & 7) * 8))];
      const bf16x8* kf1 = (const bf16x8*)&Kl[key * 64 + ((32 + g * 8) ^ ((key & 7) * 8))];
      sa[ct] = MFMA16(qf0, *kf0, sa[ct]);
      sa[ct] = MFMA16(qf1, *kf1, sa[ct]);
    }

    // ---- exp, mask, pack P (bf16), rowsum from rounded values ----
#pragma unroll
    for (int r = 0; r < 4; ++r) {
      unsigned short pb[4];
#pragma unroll
      for (int ct = 0; ct < 4; ++ct) {
        int keyg = kt * 64 + c * 4 + ct;
        unsigned short p16 = 0;
        if (keyg <= 960) p16 = f2bf(__expf(sa[ct][r]));
        pb[ct] = p16;
        rowsum[r] += bf2f(p16);
      }
      int q = g * 4 + r;
      unsigned int p01 = (unsigned int)pb[0] | ((unsigned int)pb[1] << 16);
      unsigned int p23 = (unsigned int)pb[2] | ((unsigned int)pb[3] << 16);
      int e0 = (c * 4) ^ ((q & 7) * 8);
      *(unsigned int*)&pw[q * 64 + e0] = p01;
      *(unsigned int*)&pw[q * 64 + e0 + 2] = p23;
    }
    __syncthreads();

    // ---- PV ----
#pragma unroll
    for (int kk = 0; kk < 2; ++kk) {
      bf16x8 pa = *(const bf16x8*)&pw[c * 64 + ((kk * 32 + g * 8) ^ ((c & 7) * 8))];
#pragma unroll
      for (int dt = 0; dt < 4; ++dt) {
        int d = dt * 16 + c;
        const bf16x8* vf = (const bf16x8*)&Vl[d * 64 + ((kk * 32 + g * 8) ^ ((d & 7) * 8))];
        oacc[dt] = MFMA16(pa, *vf, oacc[dt]);
      }
    }
    __syncthreads();
  }

#pragma unroll
  for (int r = 0; r < 4; ++r) {
    float s = rowsum[r];
    s += __shfl_xor(s, 1, 64);
    s += __shfl_xor(s, 2, 64);
    s += __shfl_xor(s, 4, 64);
    s += __shfl_xor(s, 8, 64);
    rowsum[r] = 1.f / s;
  }
  int nbase = n0 + w * 16 + g * 4;
  float* ob = O + (size_t)hb * 61504;
#pragma unroll
  for (int r = 0; r < 4; ++r) {
    int n = nbase + r;
    if (n > 960) continue;
#pragma unroll
    for (int dt = 0; dt < 4; ++dt)
      ob[(size_t)n * 64 + dt * 16 + c] = oacc[dt][r] * rowsum[r];
  }
}

// ---------------------------------------------------------------------------
// wfold[m] = Wp1[m,:] . Wp2   (378 MB read, HBM-bound)
// ---------------------------------------------------------------------------
__global__ __launch_bounds__(TPB) void fold_wp_k(
    const float* __restrict__ Wp1, const float* __restrict__ Wp2,
    float* __restrict__ wfold)
{
  __shared__ float w2[1536];
  int tid = threadIdx.x;
  for (int i = tid; i < 1536; i += 256) w2[i] = Wp2[i];
  __syncthreads();
  int lane = tid & 63, wv = tid >> 6;
  int m = blockIdx.x * 4 + wv;
  if (m >= 61504) return;
  const float* row = Wp1 + (size_t)m * 1536;
  float s = 0.f;
#pragma unroll
  for (int k = 0; k < 6; ++k) {
    float4 a  = *(const float4*)(row + k * 256 + lane * 4);
    float4 w4 = *(const float4*)&w2[k * 256 + lane * 4];
    s += a.x * w4.x + a.y * w4.y + a.z * w4.z + a.w * w4.w;
  }
#pragma unroll
  for (int off = 32; off >= 1; off >>= 1) s += __shfl_xor(s, off, 64);
  if (lane == 0) wfold[m] = s;
}

// ---------------------------------------------------------------------------
// out[b*12+h] = O[hb,:] . wfold + bp1 . Wp2 + bp2
// ---------------------------------------------------------------------------
__global__ __launch_bounds__(TPB) void final_k(
    const float* __restrict__ O, const float* __restrict__ wfold,
    const float* __restrict__ bp1, const float* __restrict__ Wp2,
    const float* __restrict__ bp2, float* __restrict__ out)
{
  int hb = blockIdx.x;
  int h = hb >> 3, b = hb & 7;
  int tid = threadIdx.x;
  const float* orow = O + (size_t)hb * 61504;
  float s = 0.f;
  for (int i4 = tid; i4 < 15376; i4 += 256) {
    float4 a = *(const float4*)(orow + (size_t)i4 * 4);
    float4 w = *(const float4*)(wfold + (size_t)i4 * 4);
    s += a.x * w.x + a.y * w.y + a.z * w.z + a.w * w.w;
  }
  for (int p = tid; p < 1536; p += 256) s += bp1[p] * Wp2[p];
#pragma unroll
  for (int off = 32; off >= 1; off >>= 1) s += __shfl_xor(s, off, 64);
  __shared__ float red[4];
  if ((tid & 63) == 0) red[tid >> 6] = s;
  __syncthreads();
  if (tid == 0) out[b * 12 + h] = red[0] + red[1] + red[2] + red[3] + bp2[0];
}

// ---------------------------------------------------------------------------
extern "C" void kernel_launch(void* const* d_in, const int* in_sizes, int n_in,
                              void* d_out, int out_size, void* d_ws, size_t ws_size,
                              hipStream_t stream)
{
  const float* x    = (const float*)d_in[0];
  const float* W1   = (const float*)d_in[1];
  const float* b1   = (const float*)d_in[2];
  const float* W2   = (const float*)d_in[3];
  const float* b2   = (const float*)d_in[4];
  const float* W3   = (const float*)d_in[5];
  const float* b3   = (const float*)d_in[6];
  const float* W4   = (const float*)d_in[7];
  const float* b4   = (const float*)d_in[8];
  const float* Wruv = (const float*)d_in[9];
  const float* bruv = (const float*)d_in[10];
  const float* Wp1  = (const float*)d_in[11];
  const float* bp1  = (const float*)d_in[12];
  const float* Wp2  = (const float*)d_in[13];
  const float* bp2  = (const float*)d_in[14];
  float* out = (float*)d_out;

  char* base = (char*)d_ws;
  size_t off = 0;
  auto alloc = [&](size_t bytes) -> void* {
    void* p = base + off;
    off = (off + bytes + 255) & ~(size_t)255;
    return p;
  };
  unsigned short* RU  = (unsigned short*)alloc((size_t)7688 * 1536 * 2);          // 23.6 MB
  unsigned short* Vt  = (unsigned short*)alloc((size_t)96 * 64 * 968 * 2 + 1024); // 11.9 MB
  float* Ob    = (float*)alloc((size_t)96 * 61504 * 4);                           // 23.6 MB
  float* aug1  = (float*)alloc(51 * 200 * 4);
  float* aug2  = (float*)alloc(51 * 200 * 4);
  float* aug3  = (float*)alloc(51 * 768 * 4);
  unsigned short* WfTh = (unsigned short*)alloc((size_t)2304 * 64 * 2);
  unsigned short* WfTl = (unsigned short*)alloc((size_t)2304 * 64 * 2);
  float* bfv   = (float*)alloc(2304 * 4);
  float* wfold = (float*)alloc(61504 * 4);
  if (off > ws_size) return;

  dim3 tb(TPB);

  // ---- fold MLP+RUV into augmented [Wf; bf] via 4 GEMMs ----
  gemm_fold_k<<<dim3(4),  tb, 0, stream>>>(W1,   b1,            W2,   b2,   aug1,    nullptr, nullptr, nullptr, 200, 200, 0);
  gemm_fold_k<<<dim3(4),  tb, 0, stream>>>(aug1, aug1 + 50*200, W3,   b3,   aug2,    nullptr, nullptr, nullptr, 200, 200, 0);
  gemm_fold_k<<<dim3(12), tb, 0, stream>>>(aug2, aug2 + 50*200, W4,   b4,   aug3,    nullptr, nullptr, nullptr, 200, 768, 0);
  gemm_fold_k<<<dim3(36), tb, 0, stream>>>(aug3, aug3 + 50*768, Wruv, bruv, nullptr, WfTh,    WfTl,    bfv,     768, 2304, 1);

  // ---- ruv = x @ Wf + bf (split-bf16 MFMA) -> RU + transposed Vt ----
  gemm_ruv_mfma_k<<<dim3(9, 121), tb, 0, stream>>>(x, WfTh, WfTl, bfv, RU, Vt);

  // ---- MFMA flash attention (QB=128, 512 threads) ----
  attn_mfma_k<<<dim3(8, 96), dim3(TPA), 0, stream>>>(RU, Vt, Ob);

  // ---- fold Wp1 @ Wp2 ----
  fold_wp_k<<<dim3(15376), tb, 0, stream>>>(Wp1, Wp2, wfold);

  // ---- final scalar per (h,b) ----
  final_k<<<dim3(96), tb, 0, stream>>>(Ob, wfold, bp1, Wp2, bp2, out);
}

// Round 9
// 489.230 us; speedup vs baseline: 1.0419x; 1.0419x over previous
//
#include <hip/hip_runtime.h>
#include <hip/hip_bf16.h>

#define TPB 256

typedef __attribute__((ext_vector_type(8))) short bf16x8;
typedef __attribute__((ext_vector_type(4))) float f32x4;

static __device__ __forceinline__ unsigned short f2bf(float f) {
  union { float f; unsigned int u; } x; x.f = f;
  unsigned int r = x.u + 0x7FFF + ((x.u >> 16) & 1);   // RNE
  return (unsigned short)(r >> 16);
}
static __device__ __forceinline__ float bf2f(unsigned short h) {
  union { unsigned int u; float f; } x; x.u = ((unsigned int)h) << 16;
  return x.f;
}

#define MFMA16(a, b, c) __builtin_amdgcn_mfma_f32_16x16x32_bf16(a, b, c, 0, 0, 0)

// ---------------------------------------------------------------------------
// Augmented fold GEMM: C(51,Nc) = [A(50,K); lastrow(K)] @ W(K,Nc), bias added
// to row 50 only. mode 0: fp32 C row-major (51 rows).
// mode 1: rows 0..49 (51..63 zero) -> WfT_hi/WfT_lo [col][64] bf16 split,
//         k index pre-XOR-swizzled; row 50 -> bfv fp32.
// ---------------------------------------------------------------------------
__global__ __launch_bounds__(TPB) void gemm_fold_k(
    const float* __restrict__ A, const float* __restrict__ lastrow,
    const float* __restrict__ W, const float* __restrict__ bias,
    float* __restrict__ C, unsigned short* __restrict__ WfTh,
    unsigned short* __restrict__ WfTl, float* __restrict__ bfv,
    int K, int Nc, int mode)
{
  __shared__ float As[16][68];
  __shared__ float Ws[16][68];
  int tid = threadIdx.x;
  int col0 = blockIdx.x * 64;
  int ty = tid >> 4, tx = tid & 15;
  float acc[4][4] = {};
  for (int k0 = 0; k0 < K; k0 += 16) {
#pragma unroll
    for (int i = 0; i < 4; ++i) {
      int idx = tid + i * 256;
      int r = idx >> 4, kk = idx & 15;
      int gk = k0 + kk;
      float v = 0.f;
      if (gk < K) {
        if (r < 50) v = A[(size_t)r * K + gk];
        else if (r == 50) v = lastrow[gk];
      }
      As[kk][r] = v;
    }
#pragma unroll
    for (int i = 0; i < 4; ++i) {
      int idx = tid + i * 256;
      int c = idx & 63, kk = idx >> 6;
      int gc = col0 + c, gk = k0 + kk;
      float v = 0.f;
      if (gk < K && gc < Nc) v = W[(size_t)gk * Nc + gc];
      Ws[kk][c] = v;
    }
    __syncthreads();
#pragma unroll
    for (int kk = 0; kk < 16; ++kk) {
      float4 a4 = *(const float4*)&As[kk][ty * 4];
      float4 b4 = *(const float4*)&Ws[kk][tx * 4];
      float av[4] = {a4.x, a4.y, a4.z, a4.w};
      float bv[4] = {b4.x, b4.y, b4.z, b4.w};
#pragma unroll
      for (int i = 0; i < 4; ++i)
#pragma unroll
        for (int j = 0; j < 4; ++j)
          acc[i][j] = fmaf(av[i], bv[j], acc[i][j]);
    }
    __syncthreads();
  }
#pragma unroll
  for (int i = 0; i < 4; ++i) {
    int gr = ty * 4 + i;
#pragma unroll
    for (int j = 0; j < 4; ++j) {
      int gc = col0 + tx * 4 + j;
      if (gc >= Nc) continue;
      float v = acc[i][j];
      if (gr == 50) v += bias[gc];
      if (mode == 0) {
        if (gr < 51) C[(size_t)gr * Nc + gc] = v;
      } else {
        if (gr == 50) bfv[gc] = v;
        else {
          unsigned short hi = f2bf(v);
          size_t el = (size_t)gc * 64 + (gr ^ ((gc & 7) * 8));
          WfTh[el] = hi;
          WfTl[el] = f2bf(v - bf2f(hi));
        }
      }
    }
  }
}

// ---------------------------------------------------------------------------
// Split-precision MFMA ruv GEMM (unchanged from round 8).
// ---------------------------------------------------------------------------
__global__ __launch_bounds__(TPB) void gemm_ruv_mfma_k(
    const float* __restrict__ x,
    const unsigned short* __restrict__ WfTh,
    const unsigned short* __restrict__ WfTl,
    const float* __restrict__ bias,
    unsigned short* __restrict__ RU,
    unsigned short* __restrict__ Vt)
{
  __shared__ unsigned short Bl[256 * 64];
  int tid = threadIdx.x, w = tid >> 6, lane = tid & 63;
  int g = lane >> 4, c = lane & 15;
  int m0 = blockIdx.y * 64;
  int col0 = blockIdx.x * 256;
  int wc0 = w * 64;

  bf16x8 afh[4][2], afl[4][2];
#pragma unroll
  for (int rt = 0; rt < 4; ++rt) {
    int row = m0 + rt * 16 + c;
    if (row > 7687) row = 7687;
    const float* xr = x + (size_t)row * 50;
#pragma unroll
    for (int kk = 0; kk < 2; ++kk) {
      bf16x8 ah, al;
#pragma unroll
      for (int i = 0; i < 8; ++i) {
        int k = kk * 32 + g * 8 + i;
        float v = (k < 50) ? xr[k] : 0.f;
        unsigned short hi = f2bf(v);
        ah[i] = (short)hi;
        al[i] = (short)f2bf(v - bf2f(hi));
      }
      afh[rt][kk] = ah;
      afl[rt][kk] = al;
    }
  }

#pragma unroll
  for (int it = 0; it < 8; ++it) {
    int chunk = tid + it * 256;
    int colr = chunk >> 3, s = chunk & 7;
    *(int4*)&Bl[colr * 64 + s * 8] =
        *(const int4*)&WfTh[(size_t)(col0 + colr) * 64 + s * 8];
  }
  __syncthreads();

  f32x4 zero4 = {0.f, 0.f, 0.f, 0.f};
  f32x4 acc[4][4] = {{zero4, zero4, zero4, zero4}, {zero4, zero4, zero4, zero4},
                     {zero4, zero4, zero4, zero4}, {zero4, zero4, zero4, zero4}};

#pragma unroll
  for (int ct = 0; ct < 4; ++ct) {
    int bcol = wc0 + ct * 16 + c;
    int sw = (bcol & 7) * 8;
    bf16x8 b0 = *(const bf16x8*)&Bl[bcol * 64 + ((g * 8) ^ sw)];
    bf16x8 b1 = *(const bf16x8*)&Bl[bcol * 64 + ((32 + g * 8) ^ sw)];
#pragma unroll
    for (int rt = 0; rt < 4; ++rt) {
      acc[rt][ct] = MFMA16(afh[rt][0], b0, acc[rt][ct]);
      acc[rt][ct] = MFMA16(afh[rt][1], b1, acc[rt][ct]);
      acc[rt][ct] = MFMA16(afl[rt][0], b0, acc[rt][ct]);
      acc[rt][ct] = MFMA16(afl[rt][1], b1, acc[rt][ct]);
    }
  }
  __syncthreads();

#pragma unroll
  for (int it = 0; it < 8; ++it) {
    int chunk = tid + it * 256;
    int colr = chunk >> 3, s = chunk & 7;
    *(int4*)&Bl[colr * 64 + s * 8] =
        *(const int4*)&WfTl[(size_t)(col0 + colr) * 64 + s * 8];
  }
  __syncthreads();

#pragma unroll
  for (int ct = 0; ct < 4; ++ct) {
    int bcol = wc0 + ct * 16 + c;
    int sw = (bcol & 7) * 8;
    bf16x8 b0 = *(const bf16x8*)&Bl[bcol * 64 + ((g * 8) ^ sw)];
    bf16x8 b1 = *(const bf16x8*)&Bl[bcol * 64 + ((32 + g * 8) ^ sw)];
#pragma unroll
    for (int rt = 0; rt < 4; ++rt) {
      acc[rt][ct] = MFMA16(afh[rt][0], b0, acc[rt][ct]);
      acc[rt][ct] = MFMA16(afh[rt][1], b1, acc[rt][ct]);
    }
  }

  bool isRU = (col0 < 1536);
#pragma unroll
  for (int ct = 0; ct < 4; ++ct) {
    int col = col0 + wc0 + ct * 16 + c;
    float bs = bias[col];
    if (isRU) {
#pragma unroll
      for (int rt = 0; rt < 4; ++rt) {
        int row0 = m0 + rt * 16 + g * 4;
#pragma unroll
        for (int r = 0; r < 4; ++r) {
          int row = row0 + r;
          if (row < 7688)
            RU[(size_t)row * 1536 + col] = f2bf(acc[rt][ct][r] + bs);
        }
      }
    } else {
      int hd = col - 1536;
      int hh = hd >> 6, d = hd & 63;
#pragma unroll
      for (int rt = 0; rt < 4; ++rt) {
        int row0 = m0 + rt * 16 + g * 4;
        int b0 = row0 / 961;
        int n0 = row0 - b0 * 961;
        if (row0 + 3 < 7688 && n0 <= 957 && (n0 & 3) == 0) {
          ushort4 o;
          o.x = f2bf(acc[rt][ct][0] + bs);
          o.y = f2bf(acc[rt][ct][1] + bs);
          o.z = f2bf(acc[rt][ct][2] + bs);
          o.w = f2bf(acc[rt][ct][3] + bs);
          *(ushort4*)&Vt[((size_t)(hh * 8 + b0) * 64 + d) * 968 + n0] = o;
        } else {
#pragma unroll
          for (int r = 0; r < 4; ++r) {
            int row = row0 + r;
            if (row >= 7688) continue;
            int bb = row / 961;
            int nn = row - bb * 961;
            Vt[((size_t)(hh * 8 + bb) * 64 + d) * 968 + nn] =
                f2bf(acc[rt][ct][r] + bs);
          }
        }
      }
    }
  }
}

// ---------------------------------------------------------------------------
// Fused heterogeneous kernel: attention (every 11th block) + fold_wp (rest).
// Grid 8448 x 512 threads. Attention: QB=128, double-buffered K/V tiles,
// ONE barrier per k-tile (P is wave-private; prefetch issue-early/write-late).
// Fold: wfold[m] = Wp1[m,:].Wp2, one wave per m, grid-strided.
// ---------------------------------------------------------------------------
__global__ __launch_bounds__(512) void attn_wp_k(
    const unsigned short* __restrict__ RU,   // [b*961][1536] bf16 bits
    const unsigned short* __restrict__ Vt,   // [hb][64][968] bf16 bits
    float* __restrict__ O,                   // [hb][961*64] fp32
    const float* __restrict__ Wp1, const float* __restrict__ Wp2,
    float* __restrict__ wfold)
{
  __shared__ unsigned short sh[24576];       // 48 KB
  int bid = blockIdx.x;
  int tid = threadIdx.x;

  if ((bid % 11) != 0) {
    // ---------------- fold_wp role ----------------
    float* w2 = (float*)sh;                  // first 6 KB
    for (int i = tid; i < 1536; i += 512) w2[i] = Wp2[i];
    __syncthreads();
    int fid = bid - bid / 11 - 1;            // 0..7679
    int wv = tid >> 6, lane = tid & 63;
    for (int m8 = fid; m8 < 7688; m8 += 7680) {
      int m = m8 * 8 + wv;                   // < 61504
      const float* row = Wp1 + (size_t)m * 1536;
      float s = 0.f;
#pragma unroll
      for (int k = 0; k < 6; ++k) {
        float4 a  = *(const float4*)(row + k * 256 + lane * 4);
        float4 ww = *(const float4*)&w2[k * 256 + lane * 4];
        s += a.x * ww.x + a.y * ww.y + a.z * ww.z + a.w * ww.w;
      }
#pragma unroll
      for (int off2 = 32; off2 >= 1; off2 >>= 1) s += __shfl_xor(s, off2, 64);
      if (lane == 0) wfold[m] = s;
    }
    return;
  }

  // ---------------- attention role ----------------
  const int NS = 961, RS = 1536, VROW = 968;
  int aid = bid / 11;                        // 0..767
  int qb = aid & 7, hb = aid >> 3;
  int h = hb >> 3, b = hb & 7;
  int n0 = qb * 128;
  int w = tid >> 6, lane = tid & 63;
  int g = lane >> 4, c = lane & 15;
  const unsigned short* rubase = RU + (size_t)b * NS * RS;
  int roff = h * 64, uoff = 768 + h * 64;
  const unsigned short* vtbase = Vt + (size_t)hb * 64 * VROW;
  unsigned short* Kbuf[2] = {sh, sh + 4096};
  unsigned short* Vbuf[2] = {sh + 8192, sh + 12288};
  unsigned short* pw = sh + 16384 + w * 1024;

  int qrow = n0 + w * 16 + c;
  if (qrow > 960) qrow = 960;
  bf16x8 qf0 = *(const bf16x8*)(rubase + (size_t)qrow * RS + roff + g * 8);
  bf16x8 qf1 = *(const bf16x8*)(rubase + (size_t)qrow * RS + roff + 32 + g * 8);

  // staging geometry: 512 threads cover 64 rows x 8 chunks of 8 bf16 (16B)
  int srow = tid >> 3, ss = tid & 7;
  int sel = srow * 64 + 8 * (ss ^ (srow & 7));            // 16B-aligned
  const unsigned short* ksrc = rubase + uoff + ss * 8;    // + key*RS
  const unsigned short* vsrc = vtbase + (size_t)srow * VROW + ss * 8; // + kt*64

  // prologue: tile 0 -> buffer 0 (kt=0: key row = srow <= 63, in range)
  {
    int4 kv = *(const int4*)(ksrc + (size_t)srow * RS);
    int4 vv = *(const int4*)(vsrc);
    *(int4*)&Kbuf[0][sel] = kv;
    *(int4*)&Vbuf[0][sel] = vv;
  }
  __syncthreads();

  f32x4 zero4 = {0.f, 0.f, 0.f, 0.f};
  f32x4 oacc[4] = {zero4, zero4, zero4, zero4};
  float rowsum[4] = {0.f, 0.f, 0.f, 0.f};

  unsigned short* Kc = Kbuf[0];
  unsigned short* Vc = Vbuf[0];
  unsigned short* Kn = Kbuf[1];
  unsigned short* Vn = Vbuf[1];

  for (int kt = 0; kt < 16; ++kt) {
    // ---- issue prefetch loads for kt+1 (registers; write after compute) ----
    int4 pk, pv;
    bool pre = (kt < 15);
    if (pre) {
      int keyg = (kt + 1) * 64 + srow;
      int kcl = keyg > 960 ? 960 : keyg;
      pk = *(const int4*)(ksrc + (size_t)kcl * RS);
      pv = *(const int4*)(vsrc + (kt + 1) * 64);   // overread masked by P=0
    }

    // ---- QK^T from current K buffer ----
    f32x4 sa[4] = {zero4, zero4, zero4, zero4};
    __builtin_amdgcn_s_setprio(1);
#pragma unroll
    for (int ct = 0; ct < 4; ++ct) {
      int key = c * 4 + ct;
      int sw = (key & 7) * 8;
      bf16x8 k0 = *(const bf16x8*)&Kc[key * 64 + ((g * 8) ^ sw)];
      bf16x8 k1 = *(const bf16x8*)&Kc[key * 64 + ((32 + g * 8) ^ sw)];
      sa[ct] = MFMA16(qf0, k0, sa[ct]);
      sa[ct] = MFMA16(qf1, k1, sa[ct]);
    }
    __builtin_amdgcn_s_setprio(0);

    // ---- exp (no max), mask, pack P (wave-private -> no barrier) ----
#pragma unroll
    for (int r = 0; r < 4; ++r) {
      unsigned short pb[4];
#pragma unroll
      for (int ct = 0; ct < 4; ++ct) {
        int keyg = kt * 64 + c * 4 + ct;
        unsigned short p16 = 0;
        if (keyg <= 960) p16 = f2bf(__expf(sa[ct][r]));
        pb[ct] = p16;
        rowsum[r] += bf2f(p16);
      }
      int q = g * 4 + r;
      int e0 = (c * 4) ^ ((q & 7) * 8);
      *(unsigned int*)&pw[q * 64 + e0] =
          (unsigned int)pb[0] | ((unsigned int)pb[1] << 16);
      *(unsigned int*)&pw[q * 64 + e0 + 2] =
          (unsigned int)pb[2] | ((unsigned int)pb[3] << 16);
    }

    // ---- write prefetched tile into the alternate buffers ----
    if (pre) {
      *(int4*)&Kn[sel] = pk;
      *(int4*)&Vn[sel] = pv;
    }

    // ---- PV from current V buffer and wave-private P ----
    __builtin_amdgcn_s_setprio(1);
#pragma unroll
    for (int kk = 0; kk < 2; ++kk) {
      bf16x8 pa = *(const bf16x8*)&pw[c * 64 + ((kk * 32 + g * 8) ^ ((c & 7) * 8))];
#pragma unroll
      for (int dt = 0; dt < 4; ++dt) {
        int d = dt * 16 + c;
        bf16x8 vf = *(const bf16x8*)&Vc[d * 64 + ((kk * 32 + g * 8) ^ ((d & 7) * 8))];
        oacc[dt] = MFMA16(pa, vf, oacc[dt]);
      }
    }
    __builtin_amdgcn_s_setprio(0);

    __syncthreads();   // prefetch writes visible; current-buffer reads done
    unsigned short* t;
    t = Kc; Kc = Kn; Kn = t;
    t = Vc; Vc = Vn; Vn = t;
  }

  // ---- finalize ----
#pragma unroll
  for (int r = 0; r < 4; ++r) {
    float s = rowsum[r];
    s += __shfl_xor(s, 1, 64);
    s += __shfl_xor(s, 2, 64);
    s += __shfl_xor(s, 4, 64);
    s += __shfl_xor(s, 8, 64);
    rowsum[r] = 1.f / s;
  }
  int nbase = n0 + w * 16 + g * 4;
  float* ob = O + (size_t)hb * 61504;
#pragma unroll
  for (int r = 0; r < 4; ++r) {
    int n = nbase + r;
    if (n > 960) continue;
#pragma unroll
    for (int dt = 0; dt < 4; ++dt)
      ob[(size_t)n * 64 + dt * 16 + c] = oacc[dt][r] * rowsum[r];
  }
}

// ---------------------------------------------------------------------------
// out[b*12+h] = O[hb,:] . wfold + bp1 . Wp2 + bp2
// ---------------------------------------------------------------------------
__global__ __launch_bounds__(TPB) void final_k(
    const float* __restrict__ O, const float* __restrict__ wfold,
    const float* __restrict__ bp1, const float* __restrict__ Wp2,
    const float* __restrict__ bp2, float* __restrict__ out)
{
  int hb = blockIdx.x;
  int h = hb >> 3, b = hb & 7;
  int tid = threadIdx.x;
  const float* orow = O + (size_t)hb * 61504;
  float s = 0.f;
  for (int i4 = tid; i4 < 15376; i4 += 256) {
    float4 a = *(const float4*)(orow + (size_t)i4 * 4);
    float4 w = *(const float4*)(wfold + (size_t)i4 * 4);
    s += a.x * w.x + a.y * w.y + a.z * w.z + a.w * w.w;
  }
  for (int p = tid; p < 1536; p += 256) s += bp1[p] * Wp2[p];
#pragma unroll
  for (int off = 32; off >= 1; off >>= 1) s += __shfl_xor(s, off, 64);
  __shared__ float red[4];
  if ((tid & 63) == 0) red[tid >> 6] = s;
  __syncthreads();
  if (tid == 0) out[b * 12 + h] = red[0] + red[1] + red[2] + red[3] + bp2[0];
}

// ---------------------------------------------------------------------------
extern "C" void kernel_launch(void* const* d_in, const int* in_sizes, int n_in,
                              void* d_out, int out_size, void* d_ws, size_t ws_size,
                              hipStream_t stream)
{
  const float* x    = (const float*)d_in[0];
  const float* W1   = (const float*)d_in[1];
  const float* b1   = (const float*)d_in[2];
  const float* W2   = (const float*)d_in[3];
  const float* b2   = (const float*)d_in[4];
  const float* W3   = (const float*)d_in[5];
  const float* b3   = (const float*)d_in[6];
  const float* W4   = (const float*)d_in[7];
  const float* b4   = (const float*)d_in[8];
  const float* Wruv = (const float*)d_in[9];
  const float* bruv = (const float*)d_in[10];
  const float* Wp1  = (const float*)d_in[11];
  const float* bp1  = (const float*)d_in[12];
  const float* Wp2  = (const float*)d_in[13];
  const float* bp2  = (const float*)d_in[14];
  float* out = (float*)d_out;

  char* base = (char*)d_ws;
  size_t off = 0;
  auto alloc = [&](size_t bytes) -> void* {
    void* p = base + off;
    off = (off + bytes + 255) & ~(size_t)255;
    return p;
  };
  unsigned short* RU  = (unsigned short*)alloc((size_t)7688 * 1536 * 2);          // 23.6 MB
  unsigned short* Vt  = (unsigned short*)alloc((size_t)96 * 64 * 968 * 2 + 1024); // 11.9 MB
  float* Ob    = (float*)alloc((size_t)96 * 61504 * 4);                           // 23.6 MB
  float* aug1  = (float*)alloc(51 * 200 * 4);
  float* aug2  = (float*)alloc(51 * 200 * 4);
  float* aug3  = (float*)alloc(51 * 768 * 4);
  unsigned short* WfTh = (unsigned short*)alloc((size_t)2304 * 64 * 2);
  unsigned short* WfTl = (unsigned short*)alloc((size_t)2304 * 64 * 2);
  float* bfv   = (float*)alloc(2304 * 4);
  float* wfold = (float*)alloc(61504 * 4);
  if (off > ws_size) return;

  dim3 tb(TPB);

  // ---- fold MLP+RUV into augmented [Wf; bf] via 4 GEMMs ----
  gemm_fold_k<<<dim3(4),  tb, 0, stream>>>(W1,   b1,            W2,   b2,   aug1,    nullptr, nullptr, nullptr, 200, 200, 0);
  gemm_fold_k<<<dim3(4),  tb, 0, stream>>>(aug1, aug1 + 50*200, W3,   b3,   aug2,    nullptr, nullptr, nullptr, 200, 200, 0);
  gemm_fold_k<<<dim3(12), tb, 0, stream>>>(aug2, aug2 + 50*200, W4,   b4,   aug3,    nullptr, nullptr, nullptr, 200, 768, 0);
  gemm_fold_k<<<dim3(36), tb, 0, stream>>>(aug3, aug3 + 50*768, Wruv, bruv, nullptr, WfTh,    WfTl,    bfv,     768, 2304, 1);

  // ---- ruv = x @ Wf + bf (split-bf16 MFMA) -> RU + transposed Vt ----
  gemm_ruv_mfma_k<<<dim3(9, 121), tb, 0, stream>>>(x, WfTh, WfTl, bfv, RU, Vt);

  // ---- fused: MFMA flash attention (768 blocks) + Wp1@Wp2 fold (7680) ----
  attn_wp_k<<<dim3(8448), dim3(512), 0, stream>>>(RU, Vt, Ob, Wp1, Wp2, wfold);

  // ---- final scalar per (h,b) ----
  final_k<<<dim3(96), tb, 0, stream>>>(Ob, wfold, bp1, Wp2, bp2, out);
}